// Round 9
// baseline (886.560 us; speedup 1.0000x reference)
//
#include <hip/hip_runtime.h>
#include <math.h>

// Mesh encoder: 4x (spiral conv + ELU + sparse pool) + final GEMM.
// VERTS = [65536, 16384, 4096, 1024, 256], SEQ=9, CH=[3,32,64,128,256], B=16.
//
// R9: atomic-free. Per-call CSR (row-sorted edges, count-sorted row order);
// wave = 16 output rows x 1 batch x cs-slice; j-blocks of 4 edges share
// W registers; pool sum kept in registers (ELU+val-FMA per j); one clean
// store per row. Batch->XCD pinning (bid%8==b%8). 3-MFMA hi/lo error split.

#define SEQL 9

typedef __attribute__((ext_vector_type(8))) short bf16x8;
typedef __attribute__((ext_vector_type(4))) float f32x4;

__device__ __forceinline__ unsigned short f2bf_rne(float f) {
    unsigned u = __builtin_bit_cast(unsigned, f);
    u = (u + 0x7FFFu + ((u >> 16) & 1u)) >> 16;
    return (unsigned short)u;
}
__device__ __forceinline__ float bf2f(unsigned short h) {
    unsigned u = ((unsigned)h) << 16;
    return __builtin_bit_cast(float, u);
}

// split 8 fp32 -> bf16 hi (trunc) + bf16 lo (trunc of exact residual)
__device__ __forceinline__ void cvt8(const float* xf, bf16x8& ah, bf16x8& al) {
    unsigned hu[4], lu[4];
#pragma unroll
    for (int p = 0; p < 4; ++p) {
        const unsigned u0 = __builtin_bit_cast(unsigned, xf[2 * p]);
        const unsigned u1 = __builtin_bit_cast(unsigned, xf[2 * p + 1]);
        const float h0 = __builtin_bit_cast(float, u0 & 0xFFFF0000u);
        const float h1 = __builtin_bit_cast(float, u1 & 0xFFFF0000u);
        const float l0 = xf[2 * p] - h0;
        const float l1 = xf[2 * p + 1] - h1;
        hu[p] = __builtin_amdgcn_perm(u1, u0, 0x07060302u);
        lu[p] = __builtin_amdgcn_perm(__builtin_bit_cast(unsigned, l1),
                                      __builtin_bit_cast(unsigned, l0),
                                      0x07060302u);
    }
    struct U4 { unsigned a, b, c, d; };
    ah = __builtin_bit_cast(bf16x8, U4{hu[0], hu[1], hu[2], hu[3]});
    al = __builtin_bit_cast(bf16x8, U4{lu[0], lu[1], lu[2], lu[3]});
}

// ---------- prep kernels ----------

template<int CIN, int CINP, int COUT, int K>
__global__ __launch_bounds__(256)
void wt_prep(const float* __restrict__ W, unsigned short* __restrict__ WTh,
             unsigned short* __restrict__ WTl)
{
    const int t = blockIdx.x * 256 + threadIdx.x;
    if (t >= COUT * K) return;
    const int co = t / K, k = t % K;
    const int s = k / CINP, c = k % CINP;
    float w = (s < 9 && c < CIN) ? W[(size_t)(s * CIN + c) * COUT + co] : 0.0f;
    unsigned short h = f2bf_rne(w);
    WTh[t] = h;
    WTl[t] = f2bf_rne(w - bf2f(h));
}

__global__ __launch_bounds__(256)
void build_xp4(const float* __restrict__ x, float* __restrict__ xp4)
{
    const int t = blockIdx.x * 256 + threadIdx.x;   // 16*65536
    const float* p = x + (size_t)t * 3;
    *(float4*)(xp4 + (size_t)t * 4) = make_float4(p[0], p[1], p[2], 0.0f);
}

__global__ __launch_bounds__(256)
void build_eidx(const int* __restrict__ c0, const int* __restrict__ i0,
                const int* __restrict__ c1, const int* __restrict__ i1,
                const int* __restrict__ c2, const int* __restrict__ i2,
                const int* __restrict__ c3, const int* __restrict__ i3,
                int* __restrict__ E)   // [65280][16]
{
    const int t = blockIdx.x * 256 + threadIdx.x;
    if (t >= 65280 * 16) return;
    const int e = t >> 4, slot = t & 15;
    int v = 0;
    const int* col; const int* idx; int el;
    if (e < 49152)      { col = c0; idx = i0; el = e; }
    else if (e < 61440) { col = c1; idx = i1; el = e - 49152; }
    else if (e < 64512) { col = c2; idx = i2; el = e - 61440; }
    else                { col = c3; idx = i3; el = e - 64512; }
    if (slot < 9) v = idx[col[el] * SEQL + slot];
    E[t] = v;
}

// ---------- CSR builders ----------

__global__ __launch_bounds__(256)
void hist_edges(const int* __restrict__ r0, const int* __restrict__ r1,
                const int* __restrict__ r2, const int* __restrict__ r3,
                int* c0, int* c1, int* c2, int* c3)
{
    const int g = blockIdx.x * 256 + threadIdx.x;
    if (g < 49152)      atomicAdd(&c0[r0[g]], 1);
    else if (g < 61440) atomicAdd(&c1[r1[g - 49152]], 1);
    else if (g < 64512) atomicAdd(&c2[r2[g - 61440]], 1);
    else if (g < 65280) atomicAdd(&c3[r3[g - 64512]], 1);
}

struct ScanTasks { const int* in[8]; int* out[8]; int n[8]; };

__global__ __launch_bounds__(256)
void scan_multi(ScanTasks T, int first)
{
    const int* in  = T.in[first + blockIdx.x];
    int*       out = T.out[first + blockIdx.x];
    const int  n   = T.n[first + blockIdx.x];
    __shared__ int lds[256];
    const int tid = threadIdx.x;
    const int chunk = (n + 255) / 256;
    const int base = tid * chunk;
    int s = 0;
    for (int i = 0; i < chunk; ++i) { int p = base + i; if (p < n) s += in[p]; }
    lds[tid] = s; __syncthreads();
    int acc = s;
    for (int off = 1; off < 256; off <<= 1) {
        int t = (tid >= off) ? lds[tid - off] : 0;
        __syncthreads();
        acc += t; lds[tid] = acc;
        __syncthreads();
    }
    int run = acc - s;
    for (int i = 0; i < chunk; ++i) { int p = base + i; if (p < n) { out[p] = run; run += in[p]; } }
    if (tid == 255) out[n] = run;
}

__global__ __launch_bounds__(256)
void scatter_edges(const int* __restrict__ r0, const int* __restrict__ r1,
                   const int* __restrict__ r2, const int* __restrict__ r3,
                   const int* s0, const int* s1, const int* s2, const int* s3,
                   int* u0, int* u1, int* u2, int* u3,
                   int* p0, int* p1, int* p2, int* p3)
{
    const int g = blockIdx.x * 256 + threadIdx.x;
    if (g < 49152)      { int k = g;         int r = r0[k]; p0[s0[r] + atomicAdd(&u0[r], 1)] = k; }
    else if (g < 61440) { int k = g - 49152; int r = r1[k]; p1[s1[r] + atomicAdd(&u1[r], 1)] = k; }
    else if (g < 64512) { int k = g - 61440; int r = r2[k]; p2[s2[r] + atomicAdd(&u2[r], 1)] = k; }
    else if (g < 65280) { int k = g - 64512; int r = r3[k]; p3[s3[r] + atomicAdd(&u3[r], 1)] = k; }
}

__global__ __launch_bounds__(256)
void sort_hist(const int* __restrict__ s0, const int* __restrict__ s1,
               const int* __restrict__ s2, const int* __restrict__ s3,
               int* bn0, int* bn1, int* bn2, int* bn3)
{
    const int g = blockIdx.x * 256 + threadIdx.x;   // 21760 total
    const int* s; int* bn; int r;
    if (g < 16384)      { s = s0; bn = bn0; r = g; }
    else if (g < 20480) { s = s1; bn = bn1; r = g - 16384; }
    else if (g < 21504) { s = s2; bn = bn2; r = g - 20480; }
    else if (g < 21760) { s = s3; bn = bn3; r = g - 21504; }
    else return;
    int c = s[r + 1] - s[r]; c = c > 63 ? 63 : c;
    atomicAdd(&bn[c], 1);
}

__global__ __launch_bounds__(256)
void sort_scatter(const int* __restrict__ s0, const int* __restrict__ s1,
                  const int* __restrict__ s2, const int* __restrict__ s3,
                  const int* t0, const int* t1, const int* t2, const int* t3,
                  int* bc0, int* bc1, int* bc2, int* bc3,
                  int* ro0, int* ro1, int* ro2, int* ro3)
{
    const int g = blockIdx.x * 256 + threadIdx.x;
    const int* s; const int* t; int* bc; int* ro; int r;
    if (g < 16384)      { s = s0; t = t0; bc = bc0; ro = ro0; r = g; }
    else if (g < 20480) { s = s1; t = t1; bc = bc1; ro = ro1; r = g - 16384; }
    else if (g < 21504) { s = s2; t = t2; bc = bc2; ro = ro2; r = g - 20480; }
    else if (g < 21760) { s = s3; t = t3; bc = bc3; ro = ro3; r = g - 21504; }
    else return;
    int c = s[r + 1] - s[r]; c = c > 63 ? 63 : c;
    ro[t[c] + atomicAdd(&bc[c], 1)] = r;
}

// ---------- atomic-free conv+ELU+pool ----------
// Wave = 16 count-sorted output rows (A m-rows) x 1 batch x cs-slice.
// j-blocks of JB=4 edges (one per row) share W regs; pool accumulates in
// registers; one coalesced store per row.
template<int CIN, int CINP, int COUT, int K, int CS, int JB>
__global__ __launch_bounds__(256)
void conv_pool_csr(const float* __restrict__ xin,   // [16][NV][CINP]
                   const int* __restrict__ eidx,    // per-level [nnz][16]
                   const int* __restrict__ perm,    // row-sorted edge ids
                   const float* __restrict__ valp,  // [nnz] original order
                   const int* __restrict__ sstart,  // [NVOUT+1]
                   const int* __restrict__ ro,      // count-sorted row order
                   const unsigned short* __restrict__ WTh,
                   const unsigned short* __restrict__ WTl,
                   const float* __restrict__ bias,
                   float* __restrict__ xout,        // [16][NVOUT][COUT]
                   int NV, int NVOUT, int nnz, int RB)
{
    constexpr int NT = COUT / 16 / CS;

    const int tid  = threadIdx.x;
    const int lane = tid & 63, wid = tid >> 6;
    const int b16  = lane & 15, g = lane >> 4;

    const int bid = blockIdx.x;
    const int q   = bid & 7;
    int rr = bid >> 3;
    const int rb = rr % RB; rr /= RB;
    const int cs = rr % CS;
    const int pass = rr / CS;
    const int b   = q + 8 * pass;                 // batch (XCD-pinned)
    const int co0 = cs * (NT * 16);

    const int pos = (rb * 4 + wid) * 16 + b16;
    const int r   = ro[pos];
    const int st  = sstart[r];
    const int cnt = sstart[r + 1] - st;

    int wmax = cnt;
#pragma unroll
    for (int off = 1; off < 16; off <<= 1)
        wmax = max(wmax, __shfl_xor(wmax, off));

    float bv[NT];
#pragma unroll
    for (int nt = 0; nt < NT; ++nt) bv[nt] = bias[co0 + nt * 16 + b16];

    f32x4 pacc[NT];
#pragma unroll
    for (int nt = 0; nt < NT; ++nt) pacc[nt] = (f32x4){0.f, 0.f, 0.f, 0.f};

    for (int j0 = 0; j0 < wmax; j0 += JB) {
        int ee[JB]; float vj[JB];
#pragma unroll
        for (int jj = 0; jj < JB; ++jj) {
            const int jx = j0 + jj;
            const bool vld = jx < cnt;
            int pi = st + jx; pi = pi < nnz ? pi : nnz - 1;
            const int e = perm[pi];
            ee[jj] = e;
            vj[jj] = vld ? valp[e] : 0.0f;
        }

        f32x4 acc[JB][NT];
#pragma unroll
        for (int jj = 0; jj < JB; ++jj)
#pragma unroll
            for (int nt = 0; nt < NT; ++nt)
                acc[jj][nt] = (f32x4){bv[nt], bv[nt], bv[nt], bv[nt]};

        if constexpr (CINP == 4) {
            // L0: K=64, 2 k-steps; lane j: s = ks*8 + g*2 + j/4, c = j%4
#pragma unroll
            for (int ks = 0; ks < 2; ++ks) {
                bf16x8 wh[NT], wl[NT];
#pragma unroll
                for (int nt = 0; nt < NT; ++nt) {
                    const size_t wo = (size_t)(co0 + nt * 16 + b16) * K + ks * 32 + g * 8;
                    wh[nt] = *(const bf16x8*)(WTh + wo);
                    wl[nt] = *(const bf16x8*)(WTl + wo);
                }
                const int s0 = ks * 8 + g * 2;
#pragma unroll
                for (int jj = 0; jj < JB; ++jj) {
                    const int2 ev = *(const int2*)(eidx + ee[jj] * 16 + s0);
                    float xf[8];
                    *(float4*)&xf[0] = *(const float4*)(xin + ((size_t)b * NV + ev.x) * 4);
                    *(float4*)&xf[4] = *(const float4*)(xin + ((size_t)b * NV + ev.y) * 4);
                    bf16x8 ah, al; cvt8(xf, ah, al);
#pragma unroll
                    for (int nt = 0; nt < NT; ++nt) {
                        acc[jj][nt] = __builtin_amdgcn_mfma_f32_16x16x32_bf16(ah, wh[nt], acc[jj][nt], 0, 0, 0);
                        acc[jj][nt] = __builtin_amdgcn_mfma_f32_16x16x32_bf16(al, wh[nt], acc[jj][nt], 0, 0, 0);
                        acc[jj][nt] = __builtin_amdgcn_mfma_f32_16x16x32_bf16(ah, wl[nt], acc[jj][nt], 0, 0, 0);
                    }
                }
            }
        } else {
            constexpr int KPS = CIN / 32;
#pragma unroll 1
            for (int sq = 0; sq < 3; ++sq) {
                int4 v4[JB];
#pragma unroll
                for (int jj = 0; jj < JB; ++jj)
                    v4[jj] = *(const int4*)(eidx + ee[jj] * 16 + sq * 4);
#pragma unroll
                for (int ss = 0; ss < 4; ++ss) {
                    const int s = sq * 4 + ss;
                    if (s >= SEQL) break;
#pragma unroll
                    for (int kk = 0; kk < KPS; ++kk) {
                        const int ksl = s * KPS + kk;
                        bf16x8 wh[NT], wl[NT];
#pragma unroll
                        for (int nt = 0; nt < NT; ++nt) {
                            const size_t wo = (size_t)(co0 + nt * 16 + b16) * K + ksl * 32 + g * 8;
                            wh[nt] = *(const bf16x8*)(WTh + wo);
                            wl[nt] = *(const bf16x8*)(WTl + wo);
                        }
#pragma unroll
                        for (int jj = 0; jj < JB; ++jj) {
                            const int vi = (ss == 0) ? v4[jj].x : (ss == 1) ? v4[jj].y
                                         : (ss == 2) ? v4[jj].z : v4[jj].w;
                            const float* xp = xin + ((size_t)b * NV + vi) * CIN + kk * 32 + g * 8;
                            float xf[8];
                            *(float4*)&xf[0] = *(const float4*)xp;
                            *(float4*)&xf[4] = *(const float4*)(xp + 4);
                            bf16x8 ah, al; cvt8(xf, ah, al);
#pragma unroll
                            for (int nt = 0; nt < NT; ++nt) {
                                acc[jj][nt] = __builtin_amdgcn_mfma_f32_16x16x32_bf16(ah, wh[nt], acc[jj][nt], 0, 0, 0);
                                acc[jj][nt] = __builtin_amdgcn_mfma_f32_16x16x32_bf16(al, wh[nt], acc[jj][nt], 0, 0, 0);
                                acc[jj][nt] = __builtin_amdgcn_mfma_f32_16x16x32_bf16(ah, wl[nt], acc[jj][nt], 0, 0, 0);
                            }
                        }
                    }
                }
            }
        }

        // pool epilogue: pacc += val * ELU(conv);  D row m = g*4+qq [m89]
#pragma unroll
        for (int jj = 0; jj < JB; ++jj) {
            float va[4];
#pragma unroll
            for (int qq = 0; qq < 4; ++qq) va[qq] = __shfl(vj[jj], g * 4 + qq);
#pragma unroll
            for (int nt = 0; nt < NT; ++nt)
#pragma unroll
                for (int qq = 0; qq < 4; ++qq) {
                    float y = acc[jj][nt][qq];
                    y = (y > 0.0f) ? y : __expf(y) - 1.0f;
                    pacc[nt][qq] = fmaf(va[qq], y, pacc[nt][qq]);
                }
        }
    }

    int r4[4];
#pragma unroll
    for (int qq = 0; qq < 4; ++qq) r4[qq] = __shfl(r, g * 4 + qq);
#pragma unroll
    for (int nt = 0; nt < NT; ++nt)
#pragma unroll
        for (int qq = 0; qq < 4; ++qq)
            xout[((size_t)b * NVOUT + r4[qq]) * COUT + co0 + nt * 16 + b16] = pacc[nt][qq];
}

// ---------- final GEMM ----------
__global__ __launch_bounds__(256)
void final_gemm_partial(const float* __restrict__ x4,   // [16][65536]
                        const float* __restrict__ Wf,   // [65536][256]
                        float* __restrict__ part)       // [256][16][256]
{
    __shared__ float xs[256 * 20];
    const int j0 = blockIdx.x * 256;
    const int t  = threadIdx.x;

#pragma unroll
    for (int it = 0; it < 16; ++it)
        xs[t * 20 + it] = x4[(size_t)it * 65536 + j0 + t];
    __syncthreads();

    float acc[16];
#pragma unroll
    for (int b = 0; b < 16; ++b) acc[b] = 0.0f;

#pragma unroll 4
    for (int jj = 0; jj < 256; ++jj) {
        const float w = Wf[(size_t)(j0 + jj) * 256 + t];
#pragma unroll
        for (int b4 = 0; b4 < 4; ++b4) {
            const float4 xv = *(const float4*)(xs + jj * 20 + b4 * 4);
            acc[b4 * 4 + 0] = fmaf(xv.x, w, acc[b4 * 4 + 0]);
            acc[b4 * 4 + 1] = fmaf(xv.y, w, acc[b4 * 4 + 1]);
            acc[b4 * 4 + 2] = fmaf(xv.z, w, acc[b4 * 4 + 2]);
            acc[b4 * 4 + 3] = fmaf(xv.w, w, acc[b4 * 4 + 3]);
        }
    }
#pragma unroll
    for (int b = 0; b < 16; ++b)
        part[(size_t)blockIdx.x * 4096 + b * 256 + t] = acc[b];
}

__global__ __launch_bounds__(256)
void final_reduce(const float* __restrict__ part, const float* __restrict__ bf,
                  float* __restrict__ out)
{
    const int b = blockIdx.x, l = threadIdx.x;
    float s = 0.0f;
    for (int jb = 0; jb < 256; ++jb) s += part[(size_t)jb * 4096 + b * 256 + l];
    out[b * 256 + l] = s + bf[l];
}

// ---------- launch ----------
extern "C" void kernel_launch(void* const* d_in, const int* in_sizes, int n_in,
                              void* d_out, int out_size, void* d_ws, size_t ws_size,
                              hipStream_t stream)
{
    const float* x    = (const float*)d_in[0];
    const int*   idx0 = (const int*)d_in[1];
    const int*   row0 = (const int*)d_in[2];
    const int*   col0 = (const int*)d_in[3];
    const float* val0 = (const float*)d_in[4];
    const float* W0   = (const float*)d_in[5];
    const float* b0   = (const float*)d_in[6];
    const int*   idx1 = (const int*)d_in[7];
    const int*   row1 = (const int*)d_in[8];
    const int*   col1 = (const int*)d_in[9];
    const float* val1 = (const float*)d_in[10];
    const float* W1   = (const float*)d_in[11];
    const float* b1   = (const float*)d_in[12];
    const int*   idx2 = (const int*)d_in[13];
    const int*   row2 = (const int*)d_in[14];
    const int*   col2 = (const int*)d_in[15];
    const float* val2 = (const float*)d_in[16];
    const float* W2   = (const float*)d_in[17];
    const float* b2   = (const float*)d_in[18];
    const int*   idx3 = (const int*)d_in[19];
    const int*   row3 = (const int*)d_in[20];
    const int*   col3 = (const int*)d_in[21];
    const float* val3 = (const float*)d_in[22];
    const float* W3   = (const float*)d_in[23];
    const float* b3   = (const float*)d_in[24];
    const float* Wf   = (const float*)d_in[25];
    const float* bf   = (const float*)d_in[26];
    float* out = (float*)d_out;

    float* ws = (float*)d_ws;
    // Aliased activation timeline (float offsets):
    float* x1   = ws + 0;         // [16][16384][32]  live L0->L1
    float* xp4  = ws + 8388608;   // [16][65536][4]   live prep->L0
    float* x2   = ws + 8388608;   // [16][4096][64]   live L1->L2 (xp4 dead)
    float* x3   = ws + 0;         // [16][1024][128]  live L2->L3 (x1 dead)
    float* x4   = ws + 2097152;   // [16][256][256]   live L3->final
    float* part = ws + 3145728;   // [256][16][256]   final phase
    unsigned short* wt = (unsigned short*)(ws + 12582912);
    unsigned short *WTh0 = wt,          *WTl0 = wt + 2048;
    unsigned short *WTh1 = wt + 4096,   *WTl1 = wt + 22528;
    unsigned short *WTh2 = wt + 40960,  *WTl2 = wt + 114688;
    unsigned short *WTh3 = wt + 188416, *WTl3 = wt + 483328;  // end 778240 u16
    int* EIDX = (int*)(ws + 12972032);  // [65280][16] ints
    int* E0 = EIDX;
    int* E1 = EIDX + 49152 * 16;
    int* E2 = EIDX + 61440 * 16;
    int* E3 = EIDX + 64512 * 16;
    // CSR tables after EIDX (ints)
    int* C = (int*)(ws + 14016512);
    int *c0 = C + 0,      *c1 = C + 16384,  *c2 = C + 20480,  *c3 = C + 21504;
    int *u0 = C + 21760,  *u1 = C + 38144,  *u2 = C + 42240,  *u3 = C + 43264;
    int *bn0 = C + 43520, *bn1 = C + 43584, *bn2 = C + 43648, *bn3 = C + 43712;
    int *bc0 = C + 43776, *bc1 = C + 43840, *bc2 = C + 43904, *bc3 = C + 43968;
    int *s0 = C + 44032,  *s1 = C + 60417,  *s2 = C + 64514,  *s3 = C + 65539;
    int *t0 = C + 65796,  *t1 = C + 65861,  *t2 = C + 65926,  *t3 = C + 65991;
    int *p0 = C + 66056,  *p1 = C + 115208, *p2 = C + 127496, *p3 = C + 130568;
    int *ro0 = C + 131336,*ro1 = C + 147720,*ro2 = C + 151816,*ro3 = C + 152840;
    // end: 153096 ints -> ws usage ~56.7 MB

    // ---- prep ----
    hipMemsetAsync(C, 0, (size_t)44032 * sizeof(int), stream);  // c,u,bn,bc
    wt_prep<3,   4,   32,   64><<<   8, 256, 0, stream>>>(W0, WTh0, WTl0);
    wt_prep<32,  32,  64,  288><<<  72, 256, 0, stream>>>(W1, WTh1, WTl1);
    wt_prep<64,  64,  128, 576><<< 288, 256, 0, stream>>>(W2, WTh2, WTl2);
    wt_prep<128, 128, 256, 1152><<<1152, 256, 0, stream>>>(W3, WTh3, WTl3);
    build_eidx<<<4080, 256, 0, stream>>>(col0, idx0, col1, idx1, col2, idx2,
                                         col3, idx3, EIDX);
    build_xp4<<<4096, 256, 0, stream>>>(x, xp4);

    // ---- CSR build ----
    hist_edges<<<255, 256, 0, stream>>>(row0, row1, row2, row3, c0, c1, c2, c3);
    ScanTasks T;
    T.in[0] = c0;  T.out[0] = s0; T.n[0] = 16384;
    T.in[1] = c1;  T.out[1] = s1; T.n[1] = 4096;
    T.in[2] = c2;  T.out[2] = s2; T.n[2] = 1024;
    T.in[3] = c3;  T.out[3] = s3; T.n[3] = 256;
    T.in[4] = bn0; T.out[4] = t0; T.n[4] = 64;
    T.in[5] = bn1; T.out[5] = t1; T.n[5] = 64;
    T.in[6] = bn2; T.out[6] = t2; T.n[6] = 64;
    T.in[7] = bn3; T.out[7] = t3; T.n[7] = 64;
    scan_multi<<<4, 256, 0, stream>>>(T, 0);
    scatter_edges<<<255, 256, 0, stream>>>(row0, row1, row2, row3,
                                           s0, s1, s2, s3, u0, u1, u2, u3,
                                           p0, p1, p2, p3);
    sort_hist<<<85, 256, 0, stream>>>(s0, s1, s2, s3, bn0, bn1, bn2, bn3);
    scan_multi<<<4, 256, 0, stream>>>(T, 4);
    sort_scatter<<<85, 256, 0, stream>>>(s0, s1, s2, s3, t0, t1, t2, t3,
                                         bc0, bc1, bc2, bc3, ro0, ro1, ro2, ro3);

    // ---- levels (no memsets needed: every output row stored exactly once) ----
    // L0: RB=256, CS=1, NT=2; grid = 8*256*1*2 = 4096
    conv_pool_csr<3, 4, 32, 64, 1, 4><<<4096, 256, 0, stream>>>(
        xp4, E0, p0, val0, s0, ro0, WTh0, WTl0, b0, x1, 65536, 16384, 49152, 256);
    // L1: RB=64, CS=1, NT=4; grid = 8*64*1*2 = 1024
    conv_pool_csr<32, 32, 64, 288, 1, 4><<<1024, 256, 0, stream>>>(
        x1, E1, p1, val1, s1, ro1, WTh1, WTl1, b1, x2, 16384, 4096, 12288, 64);
    // L2: RB=16, CS=4, NT=2; grid = 8*16*4*2 = 1024
    conv_pool_csr<64, 64, 128, 576, 4, 4><<<1024, 256, 0, stream>>>(
        x2, E2, p2, val2, s2, ro2, WTh2, WTl2, b2, x3, 4096, 1024, 3072, 16);
    // L3: RB=4, CS=8, NT=2; grid = 8*4*8*2 = 512
    conv_pool_csr<128, 128, 256, 1152, 8, 4><<<512, 256, 0, stream>>>(
        x3, E3, p3, val3, s3, ro3, WTh3, WTl3, b3, x4, 1024, 256, 768, 4);

    // ---- final GEMM ----
    final_gemm_partial<<<256, 256, 0, stream>>>(x4, Wf, part);
    final_reduce<<<16, 256, 0, stream>>>(part, bf, out);
}

// Round 10
// 470.899 us; speedup vs baseline: 1.8827x; 1.8827x over previous
//
#include <hip/hip_runtime.h>
#include <math.h>

// Mesh encoder: 4x (spiral conv + ELU + sparse pool) + final GEMM.
// VERTS = [65536, 16384, 4096, 1024, 256], SEQ=9, CH=[3,32,64,128,256], B=16.
//
// R10: R7/R8 edge-parallel MFMA structure + (1) row-SORTED edge order
// (CSR perm) so atomic pool-adds have L2 line locality + in-register
// merging of equal-row runs, (2) higher grids (ES=2, CS tuned) for L1-L3,
// (3) batch->XCD pinning retained. 3-MFMA hi/lo error split retained.

#define SEQL 9

typedef __attribute__((ext_vector_type(8))) short bf16x8;
typedef __attribute__((ext_vector_type(4))) float f32x4;

__device__ __forceinline__ unsigned short f2bf_rne(float f) {
    unsigned u = __builtin_bit_cast(unsigned, f);
    u = (u + 0x7FFFu + ((u >> 16) & 1u)) >> 16;
    return (unsigned short)u;
}
__device__ __forceinline__ float bf2f(unsigned short h) {
    unsigned u = ((unsigned)h) << 16;
    return __builtin_bit_cast(float, u);
}

// split 8 fp32 -> bf16 hi (trunc) + bf16 lo (trunc of exact residual)
__device__ __forceinline__ void cvt8(const float* xf, bf16x8& ah, bf16x8& al) {
    unsigned hu[4], lu[4];
#pragma unroll
    for (int p = 0; p < 4; ++p) {
        const unsigned u0 = __builtin_bit_cast(unsigned, xf[2 * p]);
        const unsigned u1 = __builtin_bit_cast(unsigned, xf[2 * p + 1]);
        const float h0 = __builtin_bit_cast(float, u0 & 0xFFFF0000u);
        const float h1 = __builtin_bit_cast(float, u1 & 0xFFFF0000u);
        const float l0 = xf[2 * p] - h0;
        const float l1 = xf[2 * p + 1] - h1;
        hu[p] = __builtin_amdgcn_perm(u1, u0, 0x07060302u);
        lu[p] = __builtin_amdgcn_perm(__builtin_bit_cast(unsigned, l1),
                                      __builtin_bit_cast(unsigned, l0),
                                      0x07060302u);
    }
    struct U4 { unsigned a, b, c, d; };
    ah = __builtin_bit_cast(bf16x8, U4{hu[0], hu[1], hu[2], hu[3]});
    al = __builtin_bit_cast(bf16x8, U4{lu[0], lu[1], lu[2], lu[3]});
}

// ---------- prep ----------

template<int CIN, int CINP, int COUT, int K>
__global__ __launch_bounds__(256)
void wt_prep(const float* __restrict__ W, unsigned short* __restrict__ WTh,
             unsigned short* __restrict__ WTl)
{
    const int t = blockIdx.x * 256 + threadIdx.x;
    if (t >= COUT * K) return;
    const int co = t / K, k = t % K;
    const int s = k / CINP, c = k % CINP;
    float w = (s < 9 && c < CIN) ? W[(size_t)(s * CIN + c) * COUT + co] : 0.0f;
    unsigned short h = f2bf_rne(w);
    WTh[t] = h;
    WTl[t] = f2bf_rne(w - bf2f(h));
}

__global__ __launch_bounds__(256)
void build_xp4(const float* __restrict__ x, float* __restrict__ xp4)
{
    const int t = blockIdx.x * 256 + threadIdx.x;   // 16*65536
    const float* p = x + (size_t)t * 3;
    *(float4*)(xp4 + (size_t)t * 4) = make_float4(p[0], p[1], p[2], 0.0f);
}

// ---------- CSR builders (row-sorted edge order) ----------

__global__ __launch_bounds__(256)
void hist_edges(const int* __restrict__ r0, const int* __restrict__ r1,
                const int* __restrict__ r2, const int* __restrict__ r3,
                int* c0, int* c1, int* c2, int* c3)
{
    const int g = blockIdx.x * 256 + threadIdx.x;
    if (g < 49152)      atomicAdd(&c0[r0[g]], 1);
    else if (g < 61440) atomicAdd(&c1[r1[g - 49152]], 1);
    else if (g < 64512) atomicAdd(&c2[r2[g - 61440]], 1);
    else if (g < 65280) atomicAdd(&c3[r3[g - 64512]], 1);
}

struct ScanTasks { const int* in[4]; int* out[4]; int n[4]; };

__global__ __launch_bounds__(256)
void scan_multi(ScanTasks T)
{
    const int* in  = T.in[blockIdx.x];
    int*       out = T.out[blockIdx.x];
    const int  n   = T.n[blockIdx.x];
    __shared__ int lds[256];
    const int tid = threadIdx.x;
    const int chunk = (n + 255) / 256;
    const int base = tid * chunk;
    int s = 0;
    for (int i = 0; i < chunk; ++i) { int p = base + i; if (p < n) s += in[p]; }
    lds[tid] = s; __syncthreads();
    int acc = s;
    for (int off = 1; off < 256; off <<= 1) {
        int t = (tid >= off) ? lds[tid - off] : 0;
        __syncthreads();
        acc += t; lds[tid] = acc;
        __syncthreads();
    }
    int run = acc - s;
    for (int i = 0; i < chunk; ++i) { int p = base + i; if (p < n) { out[p] = run; run += in[p]; } }
    if (tid == 255) out[n] = run;
}

__global__ __launch_bounds__(256)
void scatter_edges(const int* __restrict__ r0, const int* __restrict__ r1,
                   const int* __restrict__ r2, const int* __restrict__ r3,
                   const int* s0, const int* s1, const int* s2, const int* s3,
                   int* u0, int* u1, int* u2, int* u3,
                   int* p0, int* p1, int* p2, int* p3)
{
    const int g = blockIdx.x * 256 + threadIdx.x;
    if (g < 49152)      { int k = g;         int r = r0[k]; p0[s0[r] + atomicAdd(&u0[r], 1)] = k; }
    else if (g < 61440) { int k = g - 49152; int r = r1[k]; p1[s1[r] + atomicAdd(&u1[r], 1)] = k; }
    else if (g < 64512) { int k = g - 61440; int r = r2[k]; p2[s2[r] + atomicAdd(&u2[r], 1)] = k; }
    else if (g < 65280) { int k = g - 64512; int r = r3[k]; p3[s3[r] + atomicAdd(&u3[r], 1)] = k; }
}

// Sorted-position tables: eidxp[pos][16] (9 spiral verts + 0-pad),
// rw[pos]=row, vl[pos]=val, in row-sorted order.
__global__ __launch_bounds__(256)
void build_sorted(const int* __restrict__ p0, const int* __restrict__ p1,
                  const int* __restrict__ p2, const int* __restrict__ p3,
                  const int* __restrict__ c0, const int* __restrict__ i0,
                  const int* __restrict__ r0, const float* __restrict__ v0,
                  const int* __restrict__ c1, const int* __restrict__ i1,
                  const int* __restrict__ r1, const float* __restrict__ v1,
                  const int* __restrict__ c2, const int* __restrict__ i2,
                  const int* __restrict__ r2, const float* __restrict__ v2,
                  const int* __restrict__ c3, const int* __restrict__ i3,
                  const int* __restrict__ r3, const float* __restrict__ v3,
                  int* __restrict__ E, int* __restrict__ RW, float* __restrict__ VL)
{
    const int t = blockIdx.x * 256 + threadIdx.x;   // 65280
    if (t >= 65280) return;
    const int* perm; const int* col; const int* idx; const int* row;
    const float* val; int lp;
    if (t < 49152)      { perm = p0; col = c0; idx = i0; row = r0; val = v0; lp = t; }
    else if (t < 61440) { perm = p1; col = c1; idx = i1; row = r1; val = v1; lp = t - 49152; }
    else if (t < 64512) { perm = p2; col = c2; idx = i2; row = r2; val = v2; lp = t - 61440; }
    else                { perm = p3; col = c3; idx = i3; row = r3; val = v3; lp = t - 64512; }
    const int e = perm[lp];
    const int cv = col[e];
    int* Ep = E + (size_t)t * 16;
#pragma unroll
    for (int s = 0; s < SEQL; ++s) Ep[s] = idx[cv * SEQL + s];
#pragma unroll
    for (int s = SEQL; s < 16; ++s) Ep[s] = 0;
    RW[t] = row[e];
    VL[t] = val[e];
}

// ---------- fused conv+ELU+pool, edge-parallel, sorted order ----------
// Wave = ES groups of 16 sorted edges x 1 batch x cs-slice of couts.
// A rows = 16 edges (lane&15); D: col=lane&15 (co), row=(lane>>4)*4+reg (edge).
template<int CIN, int CINP, int COUT, int K, int ES, int CS, int WGB>
__global__ __launch_bounds__(256)
void conv_pool_mfma(const float* __restrict__ xin,   // [16][NV][CINP]
                    const int* __restrict__ eidxp,   // [nnz][16] sorted order
                    const int* __restrict__ rw,      // [nnz] sorted rows
                    const float* __restrict__ vl,    // [nnz] sorted vals
                    const unsigned short* __restrict__ WTh,
                    const unsigned short* __restrict__ WTl,
                    const float* __restrict__ bias,
                    float* __restrict__ xout,        // [16][NVOUT][COUT], zeroed
                    int NV, int NVOUT)
{
    constexpr int NT = COUT / 16 / CS;

    const int tid  = threadIdx.x;
    const int lane = tid & 63, wid = tid >> 6;
    const int b16  = lane & 15, g = lane >> 4;

    int rr = blockIdx.x;
    const int q = rr & 7; rr >>= 3;
    const int wgb = rr % WGB; rr /= WGB;
    const int cs = rr % CS;
    const int pass = rr / CS;
    const int b   = q + 8 * pass;                 // batch (XCD-pinned, pass outermost)
    const int co0 = cs * (NT * 16);
    const int e_base = (wgb * 4 + wid) * (ES * 16);

    f32x4 acc[ES][NT];
#pragma unroll
    for (int es = 0; es < ES; ++es)
#pragma unroll
        for (int nt = 0; nt < NT; ++nt) {
            const float bv = bias[co0 + nt * 16 + b16];
            acc[es][nt] = (f32x4){bv, bv, bv, bv};
        }

    if constexpr (CINP == 4) {
        // L0: K=64, 2 k-steps; lane j: s = ks*8 + g*2 + j/4, c = j%4
#pragma unroll
        for (int ks = 0; ks < 2; ++ks) {
            bf16x8 wh[NT], wl[NT];
#pragma unroll
            for (int nt = 0; nt < NT; ++nt) {
                const size_t wo = (size_t)(co0 + nt * 16 + b16) * K + ks * 32 + g * 8;
                wh[nt] = *(const bf16x8*)(WTh + wo);
                wl[nt] = *(const bf16x8*)(WTl + wo);
            }
            const int s0 = ks * 8 + g * 2;
#pragma unroll
            for (int es = 0; es < ES; ++es) {
                const int e = e_base + es * 16 + b16;
                const int2 ev = *(const int2*)(eidxp + (size_t)e * 16 + s0);
                float xf[8];
                *(float4*)&xf[0] = *(const float4*)(xin + ((size_t)b * NV + ev.x) * 4);
                *(float4*)&xf[4] = *(const float4*)(xin + ((size_t)b * NV + ev.y) * 4);
                bf16x8 ah, al; cvt8(xf, ah, al);
#pragma unroll
                for (int nt = 0; nt < NT; ++nt) {
                    acc[es][nt] = __builtin_amdgcn_mfma_f32_16x16x32_bf16(ah, wh[nt], acc[es][nt], 0, 0, 0);
                    acc[es][nt] = __builtin_amdgcn_mfma_f32_16x16x32_bf16(al, wh[nt], acc[es][nt], 0, 0, 0);
                    acc[es][nt] = __builtin_amdgcn_mfma_f32_16x16x32_bf16(ah, wl[nt], acc[es][nt], 0, 0, 0);
                }
            }
        }
    } else {
        constexpr int KPS = CIN / 32;
#pragma unroll 1
        for (int sq = 0; sq < 3; ++sq) {
            int4 v4[ES];
#pragma unroll
            for (int es = 0; es < ES; ++es) {
                const int e = e_base + es * 16 + b16;
                v4[es] = *(const int4*)(eidxp + (size_t)e * 16 + sq * 4);
            }
#pragma unroll
            for (int ss = 0; ss < 4; ++ss) {
                const int s = sq * 4 + ss;
                if (s >= SEQL) break;
#pragma unroll
                for (int kk = 0; kk < KPS; ++kk) {
                    const int ksl = s * KPS + kk;
                    bf16x8 wh[NT], wl[NT];
#pragma unroll
                    for (int nt = 0; nt < NT; ++nt) {
                        const size_t wo = (size_t)(co0 + nt * 16 + b16) * K + ksl * 32 + g * 8;
                        wh[nt] = *(const bf16x8*)(WTh + wo);
                        wl[nt] = *(const bf16x8*)(WTl + wo);
                    }
#pragma unroll
                    for (int es = 0; es < ES; ++es) {
                        const int vi = (ss == 0) ? v4[es].x : (ss == 1) ? v4[es].y
                                     : (ss == 2) ? v4[es].z : v4[es].w;
                        const float* xp = xin + ((size_t)b * NV + vi) * CIN + kk * 32 + g * 8;
                        float xf[8];
                        *(float4*)&xf[0] = *(const float4*)xp;
                        *(float4*)&xf[4] = *(const float4*)(xp + 4);
                        bf16x8 ah, al; cvt8(xf, ah, al);
#pragma unroll
                        for (int nt = 0; nt < NT; ++nt) {
                            acc[es][nt] = __builtin_amdgcn_mfma_f32_16x16x32_bf16(ah, wh[nt], acc[es][nt], 0, 0, 0);
                            acc[es][nt] = __builtin_amdgcn_mfma_f32_16x16x32_bf16(al, wh[nt], acc[es][nt], 0, 0, 0);
                            acc[es][nt] = __builtin_amdgcn_mfma_f32_16x16x32_bf16(ah, wl[nt], acc[es][nt], 0, 0, 0);
                        }
                    }
                }
            }
        }
    }

    // Epilogue: rows are SORTED -> merge equal-row runs within the 4 m-rows,
    // then one atomic per run (L2-local thanks to global sort order).
#pragma unroll
    for (int es = 0; es < ES; ++es) {
        const int eq = e_base + es * 16 + g * 4;
        const int4   r4 = *(const int4*)(rw + eq);
        const float4 v4 = *(const float4*)(vl + eq);
        const int   ra[4] = {r4.x, r4.y, r4.z, r4.w};
        const float va[4] = {v4.x, v4.y, v4.z, v4.w};
#pragma unroll
        for (int nt = 0; nt < NT; ++nt) {
            float sum = 0.0f;
#pragma unroll
            for (int qq = 0; qq < 4; ++qq) {
                float y = acc[es][nt][qq];
                y = (y > 0.0f) ? y : __expf(y) - 1.0f;
                sum = fmaf(va[qq], y, sum);
                if (qq == 3 || ra[qq + 1] != ra[qq]) {
                    atomicAdd(xout + ((size_t)b * NVOUT + ra[qq]) * COUT + co0 + nt * 16 + b16, sum);
                    sum = 0.0f;
                }
            }
        }
    }
}

// ---------- final GEMM ----------
__global__ __launch_bounds__(256)
void final_gemm_partial(const float* __restrict__ x4,   // [16][65536]
                        const float* __restrict__ Wf,   // [65536][256]
                        float* __restrict__ part)       // [256][16][256]
{
    __shared__ float xs[256 * 20];
    const int j0 = blockIdx.x * 256;
    const int t  = threadIdx.x;

#pragma unroll
    for (int it = 0; it < 16; ++it)
        xs[t * 20 + it] = x4[(size_t)it * 65536 + j0 + t];
    __syncthreads();

    float acc[16];
#pragma unroll
    for (int b = 0; b < 16; ++b) acc[b] = 0.0f;

#pragma unroll 4
    for (int jj = 0; jj < 256; ++jj) {
        const float w = Wf[(size_t)(j0 + jj) * 256 + t];
#pragma unroll
        for (int b4 = 0; b4 < 4; ++b4) {
            const float4 xv = *(const float4*)(xs + jj * 20 + b4 * 4);
            acc[b4 * 4 + 0] = fmaf(xv.x, w, acc[b4 * 4 + 0]);
            acc[b4 * 4 + 1] = fmaf(xv.y, w, acc[b4 * 4 + 1]);
            acc[b4 * 4 + 2] = fmaf(xv.z, w, acc[b4 * 4 + 2]);
            acc[b4 * 4 + 3] = fmaf(xv.w, w, acc[b4 * 4 + 3]);
        }
    }
#pragma unroll
    for (int b = 0; b < 16; ++b)
        part[(size_t)blockIdx.x * 4096 + b * 256 + t] = acc[b];
}

__global__ __launch_bounds__(256)
void final_reduce(const float* __restrict__ part, const float* __restrict__ bf,
                  float* __restrict__ out)
{
    const int b = blockIdx.x, l = threadIdx.x;
    float s = 0.0f;
    for (int jb = 0; jb < 256; ++jb) s += part[(size_t)jb * 4096 + b * 256 + l];
    out[b * 256 + l] = s + bf[l];
}

// ---------- launch ----------
extern "C" void kernel_launch(void* const* d_in, const int* in_sizes, int n_in,
                              void* d_out, int out_size, void* d_ws, size_t ws_size,
                              hipStream_t stream)
{
    const float* x    = (const float*)d_in[0];
    const int*   idx0 = (const int*)d_in[1];
    const int*   row0 = (const int*)d_in[2];
    const int*   col0 = (const int*)d_in[3];
    const float* val0 = (const float*)d_in[4];
    const float* W0   = (const float*)d_in[5];
    const float* b0   = (const float*)d_in[6];
    const int*   idx1 = (const int*)d_in[7];
    const int*   row1 = (const int*)d_in[8];
    const int*   col1 = (const int*)d_in[9];
    const float* val1 = (const float*)d_in[10];
    const float* W1   = (const float*)d_in[11];
    const float* b1   = (const float*)d_in[12];
    const int*   idx2 = (const int*)d_in[13];
    const int*   row2 = (const int*)d_in[14];
    const int*   col2 = (const int*)d_in[15];
    const float* val2 = (const float*)d_in[16];
    const float* W2   = (const float*)d_in[17];
    const float* b2   = (const float*)d_in[18];
    const int*   idx3 = (const int*)d_in[19];
    const int*   row3 = (const int*)d_in[20];
    const int*   col3 = (const int*)d_in[21];
    const float* val3 = (const float*)d_in[22];
    const float* W3   = (const float*)d_in[23];
    const float* b3   = (const float*)d_in[24];
    const float* Wf   = (const float*)d_in[25];
    const float* bf   = (const float*)d_in[26];
    float* out = (float*)d_out;

    float* ws = (float*)d_ws;
    // Aliased activation timeline (float offsets):
    float* x1   = ws + 0;         // [16][16384][32]  live L0->L1
    float* xp4  = ws + 8388608;   // [16][65536][4]   live prep->L0
    float* x2   = ws + 8388608;   // [16][4096][64]   live L1->L2 (xp4 dead)
    float* x3   = ws + 0;         // [16][1024][128]  live L2->L3 (x1 dead)
    float* x4   = ws + 2097152;   // [16][256][256]   live L3->final
    float* part = ws + 3145728;   // [256][16][256]   final phase
    unsigned short* wt = (unsigned short*)(ws + 12582912);
    unsigned short *WTh0 = wt,          *WTl0 = wt + 2048;
    unsigned short *WTh1 = wt + 4096,   *WTl1 = wt + 22528;
    unsigned short *WTh2 = wt + 40960,  *WTl2 = wt + 114688;
    unsigned short *WTh3 = wt + 188416, *WTl3 = wt + 483328;  // end 778240 u16
    int* EIDXP = (int*)(ws + 12972032);   // [65280][16]
    int* E0 = EIDXP;
    int* E1 = EIDXP + 49152 * 16;
    int* E2 = EIDXP + 61440 * 16;
    int* E3 = EIDXP + 64512 * 16;
    int* RW = (int*)(ws + 14016512);      // [65280]
    int *R0 = RW, *R1 = RW + 49152, *R2 = RW + 61440, *R3 = RW + 64512;
    float* VL = (ws + 14081792);          // [65280]
    float *V0 = VL, *V1 = VL + 49152, *V2 = VL + 61440, *V3 = VL + 64512;
    int* C = (int*)(ws + 14147072);       // CSR scratch
    int *c0 = C + 0,     *c1 = C + 16384, *c2 = C + 20480, *c3 = C + 21504;
    int *u0 = C + 21760, *u1 = C + 38144, *u2 = C + 42240, *u3 = C + 43264;
    int *s0 = C + 43520, *s1 = C + 59905, *s2 = C + 64002, *s3 = C + 65027;
    int *p0 = C + 65284, *p1 = C + 114436, *p2 = C + 126724, *p3 = C + 129796;
    // end: C + 130564 ints -> total ws usage ~57.1 MB

    // ---- prep + CSR ----
    hipMemsetAsync(C, 0, (size_t)43520 * sizeof(int), stream);   // c*, u*
    wt_prep<3,   4,   32,   64><<<   8, 256, 0, stream>>>(W0, WTh0, WTl0);
    wt_prep<32,  32,  64,  288><<<  72, 256, 0, stream>>>(W1, WTh1, WTl1);
    wt_prep<64,  64,  128, 576><<< 288, 256, 0, stream>>>(W2, WTh2, WTl2);
    wt_prep<128, 128, 256, 1152><<<1152, 256, 0, stream>>>(W3, WTh3, WTl3);
    build_xp4<<<4096, 256, 0, stream>>>(x, xp4);

    hist_edges<<<255, 256, 0, stream>>>(row0, row1, row2, row3, c0, c1, c2, c3);
    ScanTasks T;
    T.in[0] = c0; T.out[0] = s0; T.n[0] = 16384;
    T.in[1] = c1; T.out[1] = s1; T.n[1] = 4096;
    T.in[2] = c2; T.out[2] = s2; T.n[2] = 1024;
    T.in[3] = c3; T.out[3] = s3; T.n[3] = 256;
    scan_multi<<<4, 256, 0, stream>>>(T);
    scatter_edges<<<255, 256, 0, stream>>>(row0, row1, row2, row3,
                                           s0, s1, s2, s3, u0, u1, u2, u3,
                                           p0, p1, p2, p3);
    build_sorted<<<255, 256, 0, stream>>>(p0, p1, p2, p3,
                                          col0, idx0, row0, val0,
                                          col1, idx1, row1, val1,
                                          col2, idx2, row2, val2,
                                          col3, idx3, row3, val3,
                                          EIDXP, RW, VL);

    // ---- levels ----
    // L0: ES=4, CS=1, NT=2, WGB=192 -> grid 8*192*1*2 = 3072
    hipMemsetAsync(x1, 0, (size_t)8388608 * 4, stream);
    conv_pool_mfma<3, 4, 32, 64, 4, 1, 192><<<3072, 256, 0, stream>>>(
        xp4, E0, R0, V0, WTh0, WTl0, b0, x1, 65536, 16384);

    // L1: ES=2, CS=1, NT=4, WGB=96 -> grid 8*96*1*2 = 1536
    hipMemsetAsync(x2, 0, (size_t)4194304 * 4, stream);
    conv_pool_mfma<32, 32, 64, 288, 2, 1, 96><<<1536, 256, 0, stream>>>(
        x1, E1, R1, V1, WTh1, WTl1, b1, x2, 16384, 4096);

    // L2 + L3 (x1 dead -> zero x3|x4 region in one memset)
    hipMemsetAsync(x3, 0, (size_t)3145728 * 4, stream);
    // L2: ES=2, CS=4, NT=2, WGB=24 -> grid 8*24*4*2 = 1536
    conv_pool_mfma<64, 64, 128, 576, 2, 4, 24><<<1536, 256, 0, stream>>>(
        x2, E2, R2, V2, WTh2, WTl2, b2, x3, 4096, 1024);
    // L3: ES=2, CS=8, NT=2, WGB=6 -> grid 8*6*8*2 = 768
    conv_pool_mfma<128, 128, 256, 1152, 2, 8, 6><<<768, 256, 0, stream>>>(
        x3, E3, R3, V3, WTh3, WTl3, b3, x4, 1024, 256);

    // ---- final GEMM ----
    final_gemm_partial<<<256, 256, 0, stream>>>(x4, Wf, part);
    final_reduce<<<16, 256, 0, stream>>>(part, bf, out);
}